// Round 5
// baseline (364.690 us; speedup 1.0000x reference)
//
#include <hip/hip_runtime.h>

// ECE over N=32M samples, n_bins=10.
// Round 5: rounds 1/3/4 all pinned at ~135-150us (2.7 TB/s combined traffic,
// VALUBusy ~31%, insensitive to L3 warmth) -> wave-stall bound. This version:
//  - thread-private LDS histogram columns, ds_add_u32 no-return atomics
//    (2 LDS ops/elem, no ballot/vcc chains, no RMW read latency)
//  - column stride 11 words: gcd(11,32)=1 -> 2-way bank alias = free
//  - 2x unrolled loads, 6 dwordx4 in flight per wave
//  - conf accumulated as 8.24 fixed point u32 (err <= 6e-8/elem)
// Binning (validated round 3): ei=trunc(v*10), +/-1 fixup vs exact f32
// boundaries b_j = (float)j*0.1f, strict b_j < v (== linspace+searchsorted left).

#define NBLK 2048
#define TPB  256
#define NTH  (NBLK * TPB)
#define MAXB 256
#define STR  11
#define PLANE (TPB * STR)
#define FIXS 16777216.0f
#define FIXI (1.0f / 16777216.0f)

__global__ __launch_bounds__(TPB) void ece_partial(
    const float* __restrict__ conf, const int* __restrict__ pred,
    const int* __restrict__ lab, const int* __restrict__ nbins_p,
    int n, int cap,
    float* __restrict__ ws_cnt, float* __restrict__ ws_acc,
    float* __restrict__ ws_conf)
{
  __shared__ unsigned sA[PLANE];  // packed (cnt<<16)|acc, per-thread column
  __shared__ unsigned sB[PLANE];  // conf sum, 8.24 fixed point, per-thread column
  __shared__ float l_c[TPB / 64][10], l_a[TPB / 64][10], l_t[TPB / 64][10];

  const int nb  = nbins_p[0];
  const int tid = blockIdx.x * blockDim.x + threadIdx.x;
  const int col = threadIdx.x * STR;

#define ELEM(vx, px, lx)                                              \
  { float v = (vx);                                                   \
    int ei = (int)(v * 10.0f);                                        \
    float fe = (float)ei;                                             \
    int bin = ei + (((fe + 1.0f) * 0.1f < v) ? 1 : 0)                 \
                 - ((fe * 0.1f < v) ? 0 : 1);                         \
    bin = bin < 0 ? 0 : (bin > 9 ? 9 : bin);                          \
    unsigned inc = ((px) == (lx)) ? 0x10001u : 0x10000u;              \
    atomicAdd(&sA[col + bin], inc);                                   \
    atomicAdd(&sB[col + bin], (unsigned)(v * FIXS)); }

  if (nb == 10 && cap >= 10) {
    // zero own columns (thread-private -> no barrier needed)
#pragma unroll
    for (int j = 0; j < STR; ++j) { sA[col + j] = 0u; sB[col + j] = 0u; }

    const int n4 = n >> 2;
    const float4* cp4 = (const float4*)conf;
    const int4*   pp4 = (const int4*)pred;
    const int4*   lp4 = (const int4*)lab;

    // main loop: 2x unroll, all 6 vec4 loads issued before any compute
    const int iters2 = n4 / (2 * NTH);
    int i = tid;
    for (int k = 0; k < iters2; ++k, i += 2 * NTH) {
      float4 c0 = cp4[i];       int4 p0 = pp4[i];       int4 l0 = lp4[i];
      float4 c1 = cp4[i + NTH]; int4 p1 = pp4[i + NTH]; int4 l1 = lp4[i + NTH];
      ELEM(c0.x, p0.x, l0.x) ELEM(c0.y, p0.y, l0.y)
      ELEM(c0.z, p0.z, l0.z) ELEM(c0.w, p0.w, l0.w)
      ELEM(c1.x, p1.x, l1.x) ELEM(c1.y, p1.y, l1.y)
      ELEM(c1.z, p1.z, l1.z) ELEM(c1.w, p1.w, l1.w)
    }
    // leftover vec4s
    for (int r = 2 * NTH * iters2 + tid; r < n4; r += NTH) {
      float4 c = cp4[r]; int4 p = pp4[r]; int4 l = lp4[r];
      ELEM(c.x, p.x, l.x) ELEM(c.y, p.y, l.y)
      ELEM(c.z, p.z, l.z) ELEM(c.w, p.w, l.w)
    }
    // scalar tail (divergence-safe: no wave collectives in ELEM)
    for (int s = (n4 << 2) + tid; s < n; s += NTH) {
      ELEM(conf[s], pred[s], lab[s])
    }

    // per-wave shuffle reduce of the private columns, then cross-wave via LDS
    const int lane = threadIdx.x & 63;
    const int wv   = threadIdx.x >> 6;
#pragma unroll
    for (int j = 0; j < 10; ++j) {
      unsigned pa = sA[col + j];
      unsigned qb = sB[col + j];
      float cc = (float)(pa >> 16);
      float ac = (float)(pa & 0xFFFFu);
      float tb = (float)qb * FIXI;
#pragma unroll
      for (int d = 32; d > 0; d >>= 1) {
        cc += __shfl_xor(cc, d, 64);
        ac += __shfl_xor(ac, d, 64);
        tb += __shfl_xor(tb, d, 64);
      }
      if (lane == 0) { l_c[wv][j] = cc; l_a[wv][j] = ac; l_t[wv][j] = tb; }
    }
    __syncthreads();
    if (threadIdx.x < 10) {
      float sc = 0.f, sa = 0.f, st = 0.f;
#pragma unroll
      for (int w = 0; w < TPB / 64; ++w) {
        sc += l_c[w][threadIdx.x];
        sa += l_a[w][threadIdx.x];
        st += l_t[w][threadIdx.x];
      }
      const int o = threadIdx.x * NBLK + blockIdx.x;  // [row][block]
      ws_cnt[o]  = sc;
      ws_acc[o]  = sa;
      ws_conf[o] = st;
    }
  } else {
    // ---------------- generic fallback: LDS-atomic privatized histogram ----------------
    // alias fallback histograms onto sA/sB storage (paths are exclusive)
    unsigned* g_cnt = sA;            // [MAXB]
    unsigned* g_acc = sA + MAXB;     // [MAXB]
    float*    g_conf = (float*)sB;   // [MAXB]
    int nbc = nb < 1 ? 1 : nb;
    if (nbc > MAXB) nbc = MAXB;
    if (nbc > cap) nbc = (cap < 1) ? 1 : cap;
    for (int j = threadIdx.x; j < nbc; j += blockDim.x) { g_cnt[j] = 0u; g_acc[j] = 0u; g_conf[j] = 0.0f; }
    __syncthreads();
    const float delta = 1.0f / (float)nb;
    for (int i2 = tid; i2 < n; i2 += NTH) {
      float v = conf[i2];
      int okk = (pred[i2] == lab[i2]);
      int bin = (int)(v * (float)nb);
      if (bin > nb - 1) bin = nb - 1;
      if (bin < 0) bin = 0;
      while (bin < nb - 1 && (float)(bin + 1) * delta < v) ++bin;
      while (bin > 0 && !((float)bin * delta < v)) --bin;
      if (bin > nbc - 1) bin = nbc - 1;
      atomicAdd(&g_cnt[bin], 1u);
      atomicAdd(&g_acc[bin], (unsigned)okk);
      atomicAdd(&g_conf[bin], v);
    }
    __syncthreads();
    for (int j = threadIdx.x; j < nbc; j += blockDim.x) {
      ws_cnt[j * NBLK + blockIdx.x]  = (float)g_cnt[j];
      ws_acc[j * NBLK + blockIdx.x]  = (float)g_acc[j];
      ws_conf[j * NBLK + blockIdx.x] = g_conf[j];
    }
  }
#undef ELEM
}

__global__ __launch_bounds__(640) void ece_final(
    const float* __restrict__ ws_cnt, const float* __restrict__ ws_acc,
    const float* __restrict__ ws_conf, const int* __restrict__ nbins_p,
    int n, int cap, float* __restrict__ out)
{
  int nb = nbins_p[0];
  if (nb < 1) nb = 1;
  int mx = cap < MAXB ? cap : MAXB;
  if (nb > mx) nb = mx;
  const int wv   = threadIdx.x >> 6;
  const int lane = threadIdx.x & 63;
  __shared__ double C[MAXB], A[MAXB], T[MAXB];
  for (int j = threadIdx.x; j < MAXB; j += blockDim.x) { C[j] = 0.0; A[j] = 0.0; T[j] = 0.0; }
  __syncthreads();

  for (int row = wv; row < nb; row += 10) {
    const float4* c4 = (const float4*)(ws_cnt  + (size_t)row * NBLK);
    const float4* a4 = (const float4*)(ws_acc  + (size_t)row * NBLK);
    const float4* t4 = (const float4*)(ws_conf + (size_t)row * NBLK);
    double sc = 0.0, sa = 0.0, st = 0.0;
#pragma unroll
    for (int itr = 0; itr < NBLK / 256; ++itr) {  // 8 iters of 64 lanes * float4
      float4 a = c4[itr * 64 + lane];
      float4 b = a4[itr * 64 + lane];
      float4 f = t4[itr * 64 + lane];
      sc += ((double)a.x + (double)a.y) + ((double)a.z + (double)a.w);
      sa += ((double)b.x + (double)b.y) + ((double)b.z + (double)b.w);
      st += ((double)f.x + (double)f.y) + ((double)f.z + (double)f.w);
    }
#pragma unroll
    for (int d = 32; d > 0; d >>= 1) {
      sc += __shfl_xor(sc, d, 64);
      sa += __shfl_xor(sa, d, 64);
      st += __shfl_xor(st, d, 64);
    }
    if (lane == 0) { C[row] = sc; A[row] = sa; T[row] = st; }
  }
  __syncthreads();
  if (threadIdx.x == 0) {
    double e = 0.0;
    for (int j = 0; j < nb; ++j) {
      double cn = C[j];
      if (cn > 0.0) e += fabs(T[j] / cn - A[j] / cn) * (cn / (double)n);
    }
    out[0] = (float)e;
  }
}

extern "C" void kernel_launch(void* const* d_in, const int* in_sizes, int n_in,
                              void* d_out, int out_size, void* d_ws, size_t ws_size,
                              hipStream_t stream) {
  const float* conf = (const float*)d_in[0];
  const int*   pred = (const int*)d_in[1];
  const int*   lab  = (const int*)d_in[2];
  const int*   nbp  = (const int*)d_in[3];
  const int n = in_sizes[0];

  size_t per = ws_size / 3;
  int cap = (int)(per / ((size_t)NBLK * sizeof(float)));
  if (cap > MAXB) cap = MAXB;
  float* ws_cnt  = (float*)d_ws;
  float* ws_acc  = (float*)((char*)d_ws + (size_t)cap * NBLK * sizeof(float));
  float* ws_conf = (float*)((char*)d_ws + 2ull * (size_t)cap * NBLK * sizeof(float));

  ece_partial<<<NBLK, TPB, 0, stream>>>(conf, pred, lab, nbp, n, cap, ws_cnt, ws_acc, ws_conf);
  ece_final<<<1, 640, 0, stream>>>(ws_cnt, ws_acc, ws_conf, nbp, n, cap, (float*)d_out);
}